// Round 1
// baseline (8195.813 us; speedup 1.0000x reference)
//
#include <hip/hip_runtime.h>
#include <cstdint>
#include <cstddef>
#include <math.h>

#define NROWS 65536
#define DIM   512
#define KCB   256
#define RPB   16    // rows per block (fused kernel)
#define THR   512   // threads per block (fused kernel)

// ---------------- Threefry-2x32 (jax partitionable; confirmed by R1 bulk match) ----------------
__host__ __device__ __forceinline__ uint32_t tf_rotl(uint32_t x, uint32_t r) {
  return (x << r) | (x >> (32u - r));
}
__host__ __device__ inline void tf2x32(uint32_t k0, uint32_t k1,
                                       uint32_t x0, uint32_t x1,
                                       uint32_t& o0, uint32_t& o1) {
  uint32_t k2 = k0 ^ k1 ^ 0x1BD11BDAu;
  x0 += k0; x1 += k1;
#define TF_R(r) { x0 += x1; x1 = tf_rotl(x1, r); x1 ^= x0; }
  TF_R(13) TF_R(15) TF_R(26) TF_R(6)
  x0 += k1; x1 += k2 + 1u;
  TF_R(17) TF_R(29) TF_R(16) TF_R(24)
  x0 += k2; x1 += k0 + 2u;
  TF_R(13) TF_R(15) TF_R(26) TF_R(6)
  x0 += k0; x1 += k1 + 3u;
  TF_R(17) TF_R(29) TF_R(16) TF_R(24)
  x0 += k1; x1 += k2 + 4u;
  TF_R(13) TF_R(15) TF_R(26) TF_R(6)
  x0 += k2; x1 += k0 + 5u;
#undef TF_R
  o0 = x0; o1 = x1;
}

// f32 gumbel, replicating np-f32: u from jax bits, then -log32(-log32(u)),
// each f32 log obtained by correctly-rounding the f64 log.
__device__ __forceinline__ float gumbel32(uint32_t k0, uint32_t k1, uint32_t j) {
  uint32_t o0, o1;
  tf2x32(k0, k1, 0u, j, o0, o1);
  uint32_t bits = o0 ^ o1;
  float f = __uint_as_float((bits >> 9) | 0x3f800000u) - 1.0f;
  if (f == 0.0f) f = 1.17549435e-38f;
  float t1 = (float)log((double)f);
  float t2 = (float)log((double)(-t1));
  return -t2;
}

__device__ __forceinline__ float exp32cr(float z) {
  return (float)exp((double)z);
}

// wave argmax: f32 value, smaller index wins ties (np first-occurrence)
__device__ __forceinline__ void argmax64(float& v, int& i) {
#pragma unroll
  for (int off = 32; off >= 1; off >>= 1) {
    float ov = __shfl_xor(v, off);
    int   oi = __shfl_xor(i, off);
    if (ov > v || (ov == v && oi < i)) { v = ov; i = oi; }
  }
}

// exact numpy pairwise_sum base case for n=128 (8-acc unroll + fixed combine tree)
__device__ float pw128(const float* a) {
  float r0 = a[0], r1 = a[1], r2 = a[2], r3 = a[3];
  float r4 = a[4], r5 = a[5], r6 = a[6], r7 = a[7];
  for (int i = 8; i < 128; i += 8) {
    r0 = __fadd_rn(r0, a[i + 0]); r1 = __fadd_rn(r1, a[i + 1]);
    r2 = __fadd_rn(r2, a[i + 2]); r3 = __fadd_rn(r3, a[i + 3]);
    r4 = __fadd_rn(r4, a[i + 4]); r5 = __fadd_rn(r5, a[i + 5]);
    r6 = __fadd_rn(r6, a[i + 6]); r7 = __fadd_rn(r7, a[i + 7]);
  }
  return __fadd_rn(__fadd_rn(__fadd_rn(r0, r1), __fadd_rn(r2, r3)),
                   __fadd_rn(__fadd_rn(r4, r5), __fadd_rn(r6, r7)));
}

// ---------------- cpd[i][d][k] = (C_i @ A_i)[k][d], seq-e FMA (BLAS order) ----------------
__global__ __launch_bounds__(256) void k_cproj(const float* __restrict__ C,
                                               const float* __restrict__ A,
                                               float* __restrict__ cpd) {
  const int i = blockIdx.x >> 6;
  const int d0 = (blockIdx.x & 63) * 8;
  const int t = threadIdx.x;          // t = k
  const float* Ai = A + (size_t)i * DIM * DIM;
  const float* Ci = C + (size_t)i * KCB * DIM;
  float acc[8] = {};
  for (int e = 0; e < DIM; ++e) {
    float cv = Ci[(size_t)t * DIM + e];
#pragma unroll
    for (int dd = 0; dd < 8; ++dd)
      acc[dd] = fmaf(cv, Ai[(size_t)e * DIM + d0 + dd], acc[dd]);
  }
#pragma unroll
  for (int dd = 0; dd < 8; ++dd)
    cpd[((size_t)i * DIM + d0 + dd) * KCB + t] = acc[dd];
}

// ---------------- Fully-fused 4-stage kernel ----------------
// Rows are independent across the entire 4-stage pipeline, so one block owns
// RPB=16 rows for all stages: x lives in LDS (updated in place), out_sum lives
// in registers. LDS overlay: lg/ssbuf/pbuf all reuse the dead xp buffer.
//   xrow [16][512]  : x, live whole kernel (ph4 updates in place)
//   xp   [16][512]  : ph0b out / ph1 in; then lg=[16][256] @xp[0..4096),
//                     ssbuf=[16][256] @xp[4096..8192); then pbuf=[16][512]
struct RKeys { uint32_t kh0[4], kh1[4], ks0[4], ks1[4]; };

__global__ __launch_bounds__(THR, 4) void k_fused(
    const float* __restrict__ X,      // [65536][512] original input
    const float* __restrict__ Cb,     // [4][256][512]
    const float* __restrict__ A,      // [4][512][512]
    const float* __restrict__ Wr,     // [512][512]
    const float* __restrict__ cpd,    // [4][512][256]
    float* __restrict__ out, RKeys rk) {
  __shared__ __align__(16) float xrow[RPB * 512];
  __shared__ __align__(16) float xp[RPB * 512];
  __shared__ int selL[RPB]; __shared__ int idxL[RPB]; __shared__ float wsL[RPB];
  const int t = threadIdx.x;
  const int n0 = blockIdx.x * RPB;

  // stage x rows once (float4, coalesced)
  {
    const float4* src = (const float4*)(X + (size_t)n0 * 512);
    float4* dst = (float4*)xrow;
#pragma unroll
    for (int q = 0; q < 4; ++q) dst[q * 512 + t] = src[q * 512 + t];
  }
  float osum[RPB];
#pragma unroll
  for (int r = 0; r < RPB; ++r) osum[r] = 0.0f;
  __syncthreads();

  const int kk = t & 255;        // col-thread id (256)
  const int rg = (t >> 8) * 8;   // row-group base: rows rg..rg+7

  for (int i = 0; i < 4; ++i) {
    const float* Ai   = A   + (size_t)i * DIM * DIM;
    const float* cpdi = cpd + (size_t)i * DIM * KCB;
    const float* Cbi  = Cb  + (size_t)i * KCB * DIM;

    // ph0b: xp[n][d] = seq-e FMA of x[n][e]*A[e][d] (BLAS sgemm order)
    {
      const int d0 = 2 * kk;
      float acc[8][2];
#pragma unroll
      for (int rr = 0; rr < 8; ++rr) { acc[rr][0] = 0.0f; acc[rr][1] = 0.0f; }
      for (int e = 0; e < 512; e += 2) {
        float2 a0 = *(const float2*)&Ai[(size_t)e * 512 + d0];
        float2 a1 = *(const float2*)&Ai[(size_t)(e + 1) * 512 + d0];
#pragma unroll
        for (int rr = 0; rr < 8; ++rr) {
          float2 xv = *(const float2*)&xrow[(rg + rr) * 512 + e];
          acc[rr][0] = fmaf(xv.x, a0.x, acc[rr][0]);
          acc[rr][1] = fmaf(xv.x, a0.y, acc[rr][1]);
          acc[rr][0] = fmaf(xv.y, a1.x, acc[rr][0]);
          acc[rr][1] = fmaf(xv.y, a1.y, acc[rr][1]);
        }
      }
#pragma unroll
      for (int rr = 0; rr < 8; ++rr) {
        xp[(rg + rr) * 512 + d0]     = acc[rr][0];
        xp[(rg + rr) * 512 + d0 + 1] = acc[rr][1];
      }
    }
    __syncthreads();

    // ph1: logit[n][k] = seq-d (mul,add) of xp[n][d]*cpd[d][k] (np.einsum order)
    {
      float lacc[8];
#pragma unroll
      for (int rr = 0; rr < 8; ++rr) lacc[rr] = 0.0f;
      for (int d = 0; d < 512; d += 2) {
        float cv0 = cpdi[(size_t)d * 256 + kk];
        float cv1 = cpdi[(size_t)(d + 1) * 256 + kk];
#pragma unroll
        for (int rr = 0; rr < 8; ++rr) {
          float2 xv = *(const float2*)&xp[(rg + rr) * 512 + d];
          lacc[rr] = __fadd_rn(lacc[rr], __fmul_rn(xv.x, cv0));
          lacc[rr] = __fadd_rn(lacc[rr], __fmul_rn(xv.y, cv1));
        }
      }
      __syncthreads();   // all xp reads done before lg overlays xp[0..4096)
#pragma unroll
      for (int rr = 0; rr < 8; ++rr) xp[(rg + rr) * 256 + kk] = lacc[rr];
    }
    __syncthreads();

    // ph2: per-row decisions (wave owns 2 rows; lane c owns k = sub*64+c)
    {
      float* lgb   = xp;              // [16][256]
      float* ssbuf = xp + RPB * 256;  // [16][256]
      const int c = t & 63;
      const uint32_t kh0v = rk.kh0[i], kh1v = rk.kh1[i];
      const uint32_t ks0v = rk.ks0[i], ks1v = rk.ks1[i];
#pragma unroll 1
      for (int rr2 = 0; rr2 < 2; ++rr2) {
        const int r = (t >> 6) * 2 + rr2;
        const int n = n0 + r;
        const uint32_t jb = (uint32_t)n * 256u;
        float l[4];
#pragma unroll
        for (int sub = 0; sub < 4; ++sub) l[sub] = lgb[r * 256 + sub * 64 + c];
        // idx: first-max over f32 logits
        float bv = l[0]; int bi = c;
#pragma unroll
        for (int sub = 1; sub < 4; ++sub)
          if (l[sub] > bv) { bv = l[sub]; bi = sub * 64 + c; }
        argmax64(bv, bi);
        // hard sel: first-max over (l+g_hard)/0.9f
        float sv = 0.0f; int si = 0;
#pragma unroll
        for (int sub = 0; sub < 4; ++sub) {
          float g = gumbel32(kh0v, kh1v, jb + (uint32_t)(sub * 64 + c));
          float s = __fdiv_rn(__fadd_rn(l[sub], g), 0.9f);
          if (sub == 0 || s > sv) { sv = s; si = sub * 64 + c; }
        }
        argmax64(sv, si);
        // soft: scores, row max, exp (CR f32)
        float ssv[4];
#pragma unroll
        for (int sub = 0; sub < 4; ++sub) {
          float g = gumbel32(ks0v, ks1v, jb + (uint32_t)(sub * 64 + c));
          ssv[sub] = __fdiv_rn(__fadd_rn(l[sub], g), 0.9f);
        }
        float m = fmaxf(fmaxf(ssv[0], ssv[1]), fmaxf(ssv[2], ssv[3]));
#pragma unroll
        for (int off = 32; off >= 1; off >>= 1) m = fmaxf(m, __shfl_xor(m, off));
#pragma unroll
        for (int sub = 0; sub < 4; ++sub)
          ssbuf[r * 256 + sub * 64 + c] = exp32cr(__fsub_rn(ssv[sub], m));
        if (c == 0) { selL[r] = si; idxL[r] = bi; }
      }
    }
    __syncthreads();

    // ph2b: numpy-pairwise softmax denom, ws, wstar (one thread per row)
    if (t < RPB) {
      const int r = t, n = n0 + r;
      const float* a = xp + RPB * 256 + r * 256;
      float S = __fadd_rn(pw128(a), pw128(a + 128));
      int sel = selL[r];
      float wsv = __fdiv_rn(a[sel], S);
      wsL[r] = __fadd_rn(__fsub_rn(1.0f, wsv), wsv);
      out[(size_t)NROWS * DIM + (size_t)n * 4 + i] = (float)idxL[r];
    }
    __syncthreads();

    // ph3: p = fl32(wstar * C[sel][col]); osum += p (ref stage order); pbuf = p
#pragma unroll 4
    for (int r = 0; r < RPB; ++r) {
      float p = __fmul_rn(wsL[r], Cbi[(size_t)selL[r] * 512 + t]);
      osum[r] = __fadd_rn(osum[r], p);
      if (i < 3) xp[r * 512 + t] = p;   // pbuf overlays dead lg+ssbuf
    }
    __syncthreads();

    // ph4: x <- x - p @ W_rnn (seq-d FMA), in-place in xrow
    if (i < 3) {
      const int e0 = 2 * kk;
      float acc[8][2];
#pragma unroll
      for (int rr = 0; rr < 8; ++rr) { acc[rr][0] = 0.0f; acc[rr][1] = 0.0f; }
      for (int d = 0; d < 512; d += 2) {
        float2 w0 = *(const float2*)&Wr[(size_t)d * 512 + e0];
        float2 w1 = *(const float2*)&Wr[(size_t)(d + 1) * 512 + e0];
#pragma unroll
        for (int rr = 0; rr < 8; ++rr) {
          float2 pv = *(const float2*)&xp[(rg + rr) * 512 + d];
          acc[rr][0] = fmaf(pv.x, w0.x, acc[rr][0]);
          acc[rr][1] = fmaf(pv.x, w0.y, acc[rr][1]);
          acc[rr][0] = fmaf(pv.y, w1.x, acc[rr][0]);
          acc[rr][1] = fmaf(pv.y, w1.y, acc[rr][1]);
        }
      }
#pragma unroll
      for (int rr = 0; rr < 8; ++rr) {
        const int b = (rg + rr) * 512 + e0;
        float2 xv = *(const float2*)&xrow[b];  // each (r,e) owned by one thread
        xrow[b]     = __fsub_rn(xv.x, acc[rr][0]);
        xrow[b + 1] = __fsub_rn(xv.y, acc[rr][1]);
      }
      __syncthreads();
    }
  }

  // final out_sum store (single pass)
#pragma unroll
  for (int r = 0; r < RPB; ++r)
    out[(size_t)(n0 + r) * 512 + t] = osum[r];
}

extern "C" void kernel_launch(void* const* d_in, const int* in_sizes, int n_in,
                              void* d_out, int out_size, void* d_ws, size_t ws_size,
                              hipStream_t stream) {
  const float* x  = (const float*)d_in[0];   // [65536,512]
  const float* Cb = (const float*)d_in[1];   // [4,256,512]
  const float* A  = (const float*)d_in[2];   // [4,512,512]
  const float* Wr = (const float*)d_in[3];   // [512,512]
  float* out = (float*)d_out;
  float* ws  = (float*)d_ws;

  float* cpd = ws;                           // 4*512*256 = 524288 f (2 MB)

  // keys: fold_in(key(42), i) -> split -> (k_soft = keys[0], k_hard = keys[1])
  RKeys rk;
  for (uint32_t i = 0; i < 4; ++i) {
    uint32_t f0, f1, a0, a1, b0, b1;
    tf2x32(0u, 42u, 0u, i, f0, f1);
    tf2x32(f0, f1, 0u, 0u, a0, a1);   // keys[0] -> k_soft
    tf2x32(f0, f1, 0u, 1u, b0, b1);   // keys[1] -> k_hard
    rk.ks0[i] = a0; rk.ks1[i] = a1;
    rk.kh0[i] = b0; rk.kh1[i] = b1;
  }

  k_cproj<<<dim3(256), dim3(256), 0, stream>>>(Cb, A, cpd);
  k_fused<<<dim3(NROWS / RPB), dim3(THR), 0, stream>>>(x, Cb, A, Wr, cpd, out, rk);
}

// Round 2
// 6987.389 us; speedup vs baseline: 1.1729x; 1.1729x over previous
//
#include <hip/hip_runtime.h>
#include <cstdint>
#include <cstddef>
#include <math.h>

#define NROWS 65536
#define DIM   512
#define KCB   256
#define RPB   16    // rows per block
#define THR   512   // threads per block

// ---------------- Threefry-2x32 (jax partitionable; confirmed by R1 bulk match) ----------------
__host__ __device__ __forceinline__ uint32_t tf_rotl(uint32_t x, uint32_t r) {
  return (x << r) | (x >> (32u - r));
}
__host__ __device__ inline void tf2x32(uint32_t k0, uint32_t k1,
                                       uint32_t x0, uint32_t x1,
                                       uint32_t& o0, uint32_t& o1) {
  uint32_t k2 = k0 ^ k1 ^ 0x1BD11BDAu;
  x0 += k0; x1 += k1;
#define TF_R(r) { x0 += x1; x1 = tf_rotl(x1, r); x1 ^= x0; }
  TF_R(13) TF_R(15) TF_R(26) TF_R(6)
  x0 += k1; x1 += k2 + 1u;
  TF_R(17) TF_R(29) TF_R(16) TF_R(24)
  x0 += k2; x1 += k0 + 2u;
  TF_R(13) TF_R(15) TF_R(26) TF_R(6)
  x0 += k0; x1 += k1 + 3u;
  TF_R(17) TF_R(29) TF_R(16) TF_R(24)
  x0 += k1; x1 += k2 + 4u;
  TF_R(13) TF_R(15) TF_R(26) TF_R(6)
  x0 += k2; x1 += k0 + 5u;
#undef TF_R
  o0 = x0; o1 = x1;
}

// f32 gumbel, replicating np-f32: u from jax bits, then -log32(-log32(u)),
// each f32 log obtained by correctly-rounding the f64 log.
__device__ __forceinline__ float gumbel32(uint32_t k0, uint32_t k1, uint32_t j) {
  uint32_t o0, o1;
  tf2x32(k0, k1, 0u, j, o0, o1);
  uint32_t bits = o0 ^ o1;
  float f = __uint_as_float((bits >> 9) | 0x3f800000u) - 1.0f;
  if (f == 0.0f) f = 1.17549435e-38f;
  float t1 = (float)log((double)f);
  float t2 = (float)log((double)(-t1));
  return -t2;
}

__device__ __forceinline__ float exp32cr(float z) {
  return (float)exp((double)z);
}

// wave argmax: f32 value, smaller index wins ties (np first-occurrence)
__device__ __forceinline__ void argmax64(float& v, int& i) {
#pragma unroll
  for (int off = 32; off >= 1; off >>= 1) {
    float ov = __shfl_xor(v, off);
    int   oi = __shfl_xor(i, off);
    if (ov > v || (ov == v && oi < i)) { v = ov; i = oi; }
  }
}

// exact numpy pairwise_sum base case for n=128 (8-acc unroll + fixed combine tree)
__device__ float pw128(const float* a) {
  float r0 = a[0], r1 = a[1], r2 = a[2], r3 = a[3];
  float r4 = a[4], r5 = a[5], r6 = a[6], r7 = a[7];
  for (int i = 8; i < 128; i += 8) {
    r0 = __fadd_rn(r0, a[i + 0]); r1 = __fadd_rn(r1, a[i + 1]);
    r2 = __fadd_rn(r2, a[i + 2]); r3 = __fadd_rn(r3, a[i + 3]);
    r4 = __fadd_rn(r4, a[i + 4]); r5 = __fadd_rn(r5, a[i + 5]);
    r6 = __fadd_rn(r6, a[i + 6]); r7 = __fadd_rn(r7, a[i + 7]);
  }
  return __fadd_rn(__fadd_rn(__fadd_rn(r0, r1), __fadd_rn(r2, r3)),
                   __fadd_rn(__fadd_rn(r4, r5), __fadd_rn(r6, r7)));
}

// ---------------- cpd[i][d][k] = (C_i @ A_i)[k][d], seq-e FMA (BLAS order) ----------------
__global__ __launch_bounds__(256) void k_cproj(const float* __restrict__ C,
                                               const float* __restrict__ A,
                                               float* __restrict__ cpd) {
  const int i = blockIdx.x >> 6;
  const int d0 = (blockIdx.x & 63) * 8;
  const int t = threadIdx.x;          // t = k
  const float* Ai = A + (size_t)i * DIM * DIM;
  const float* Ci = C + (size_t)i * KCB * DIM;
  float acc[8] = {};
  for (int e = 0; e < DIM; ++e) {
    float cv = Ci[(size_t)t * DIM + e];
#pragma unroll
    for (int dd = 0; dd < 8; ++dd)
      acc[dd] = fmaf(cv, Ai[(size_t)e * DIM + d0 + dd], acc[dd]);
  }
#pragma unroll
  for (int dd = 0; dd < 8; ++dd)
    cpd[((size_t)i * DIM + d0 + dd) * KCB + t] = acc[dd];
}

// ---------------- Per-stage fused: xproj -> logits -> decisions -> out RMW -> x-update ----------------
// Stage-split launches keep each stage's {Ai, cpdi, Cbi, Wr} (~3 MB) L2-resident across all
// blocks (the R1 full-fusion desynced blocks across stages and thrashed L2 -> 9 ms).
// LDS: xrow[16][512] live whole kernel; xp[16][512]+pad overlaid as lg[16][256] /
// ssbuf[16][257] / pbuf[16][512].
__global__ __launch_bounds__(THR, 4) void k_stage(
    const float* __restrict__ Xin,    // stage input x rows
    float* __restrict__ Xout,         // stage output x rows (stage<3); own-rows in-place safe
    const float* __restrict__ Ai,     // W_att[i] [512][512]
    const float* __restrict__ cpdi,   // cproj^T  [512 d][256 k]
    const float* __restrict__ Cbi,    // codebooks[i] [256][512]
    const float* __restrict__ Wr,     // W_rnn [512][512]
    float* __restrict__ out,
    uint32_t kh0, uint32_t kh1, uint32_t ks0, uint32_t ks1, int stage) {
  __shared__ __align__(16) float xrow[RPB * 512];
  __shared__ __align__(16) float xp[RPB * 512 + 32];   // +32: ssbuf row-stride 257 pad
  __shared__ int selL[RPB]; __shared__ int idxL[RPB]; __shared__ float wsL[RPB];
  const int t = threadIdx.x;
  const int n0 = blockIdx.x * RPB;

  // stage x rows (float4, coalesced)
  {
    const float4* src = (const float4*)(Xin + (size_t)n0 * 512);
    float4* dst = (float4*)xrow;
#pragma unroll
    for (int q = 0; q < 4; ++q) dst[q * 512 + t] = src[q * 512 + t];
  }
  __syncthreads();

  const int tg = t >> 7;       // 4 row-groups of 4 rows
  const int tc = t & 127;
  const int r0 = tg * 4;

  // ph0b: xp[n][d] = seq-e FMA of x[n][e]*A[e][d] (BLAS sgemm order).
  // 4 rows x 4 cols per thread; per e-quad: 4 ds_read_b128 + 4 global b128 + 64 FMA.
  {
    const int d0 = tc * 4;
    float acc[4][4];
#pragma unroll
    for (int rr = 0; rr < 4; ++rr)
#pragma unroll
      for (int c = 0; c < 4; ++c) acc[rr][c] = 0.0f;
    for (int e = 0; e < 512; e += 4) {
      float4 a0 = *(const float4*)&Ai[(size_t)(e + 0) * 512 + d0];
      float4 a1 = *(const float4*)&Ai[(size_t)(e + 1) * 512 + d0];
      float4 a2 = *(const float4*)&Ai[(size_t)(e + 2) * 512 + d0];
      float4 a3 = *(const float4*)&Ai[(size_t)(e + 3) * 512 + d0];
#pragma unroll
      for (int rr = 0; rr < 4; ++rr) {
        float4 xv = *(const float4*)&xrow[(r0 + rr) * 512 + e];
        acc[rr][0] = fmaf(xv.x, a0.x, acc[rr][0]);
        acc[rr][1] = fmaf(xv.x, a0.y, acc[rr][1]);
        acc[rr][2] = fmaf(xv.x, a0.z, acc[rr][2]);
        acc[rr][3] = fmaf(xv.x, a0.w, acc[rr][3]);
        acc[rr][0] = fmaf(xv.y, a1.x, acc[rr][0]);
        acc[rr][1] = fmaf(xv.y, a1.y, acc[rr][1]);
        acc[rr][2] = fmaf(xv.y, a1.z, acc[rr][2]);
        acc[rr][3] = fmaf(xv.y, a1.w, acc[rr][3]);
        acc[rr][0] = fmaf(xv.z, a2.x, acc[rr][0]);
        acc[rr][1] = fmaf(xv.z, a2.y, acc[rr][1]);
        acc[rr][2] = fmaf(xv.z, a2.z, acc[rr][2]);
        acc[rr][3] = fmaf(xv.z, a2.w, acc[rr][3]);
        acc[rr][0] = fmaf(xv.w, a3.x, acc[rr][0]);
        acc[rr][1] = fmaf(xv.w, a3.y, acc[rr][1]);
        acc[rr][2] = fmaf(xv.w, a3.z, acc[rr][2]);
        acc[rr][3] = fmaf(xv.w, a3.w, acc[rr][3]);
      }
    }
#pragma unroll
    for (int rr = 0; rr < 4; ++rr)
      *(float4*)&xp[(r0 + rr) * 512 + d0] =
          make_float4(acc[rr][0], acc[rr][1], acc[rr][2], acc[rr][3]);
  }
  __syncthreads();

  // ph1: logit[n][k] = seq-d (mul,add) of xp[n][d]*cpd[d][k] (np.einsum order).
  // 4 rows x 2 ks per thread; per d-quad: 4 ds_read_b128 + 4 global b64 + 64 VALU.
  {
    const int k0 = tc * 2;
    float lacc[4][2];
#pragma unroll
    for (int rr = 0; rr < 4; ++rr) { lacc[rr][0] = 0.0f; lacc[rr][1] = 0.0f; }
    for (int d = 0; d < 512; d += 4) {
      float2 c0 = *(const float2*)&cpdi[(size_t)(d + 0) * 256 + k0];
      float2 c1 = *(const float2*)&cpdi[(size_t)(d + 1) * 256 + k0];
      float2 c2 = *(const float2*)&cpdi[(size_t)(d + 2) * 256 + k0];
      float2 c3 = *(const float2*)&cpdi[(size_t)(d + 3) * 256 + k0];
#pragma unroll
      for (int rr = 0; rr < 4; ++rr) {
        float4 xv = *(const float4*)&xp[(r0 + rr) * 512 + d];
        lacc[rr][0] = __fadd_rn(lacc[rr][0], __fmul_rn(xv.x, c0.x));
        lacc[rr][1] = __fadd_rn(lacc[rr][1], __fmul_rn(xv.x, c0.y));
        lacc[rr][0] = __fadd_rn(lacc[rr][0], __fmul_rn(xv.y, c1.x));
        lacc[rr][1] = __fadd_rn(lacc[rr][1], __fmul_rn(xv.y, c1.y));
        lacc[rr][0] = __fadd_rn(lacc[rr][0], __fmul_rn(xv.z, c2.x));
        lacc[rr][1] = __fadd_rn(lacc[rr][1], __fmul_rn(xv.z, c2.y));
        lacc[rr][0] = __fadd_rn(lacc[rr][0], __fmul_rn(xv.w, c3.x));
        lacc[rr][1] = __fadd_rn(lacc[rr][1], __fmul_rn(xv.w, c3.y));
      }
    }
    __syncthreads();   // all xp reads done before lg overlays xp[0..4096)
#pragma unroll
    for (int rr = 0; rr < 4; ++rr)
      *(float2*)&xp[(r0 + rr) * 256 + k0] = make_float2(lacc[rr][0], lacc[rr][1]);
  }
  __syncthreads();

  // ph2: per-row decisions (wave owns 2 rows; lane c owns k = sub*64+c)
  {
    float* lgb   = xp;              // [16][256]
    float* ssbuf = xp + RPB * 256;  // [16][257] padded stride (bank-conflict-free pw128)
    const int c = t & 63;
#pragma unroll 1
    for (int rr2 = 0; rr2 < 2; ++rr2) {
      const int r = (t >> 6) * 2 + rr2;
      const int n = n0 + r;
      const uint32_t jb = (uint32_t)n * 256u;
      float l[4];
#pragma unroll
      for (int sub = 0; sub < 4; ++sub) l[sub] = lgb[r * 256 + sub * 64 + c];
      // idx: first-max over f32 logits
      float bv = l[0]; int bi = c;
#pragma unroll
      for (int sub = 1; sub < 4; ++sub)
        if (l[sub] > bv) { bv = l[sub]; bi = sub * 64 + c; }
      argmax64(bv, bi);
      // hard sel: first-max over (l+g_hard)/0.9f
      float sv = 0.0f; int si = 0;
#pragma unroll
      for (int sub = 0; sub < 4; ++sub) {
        float g = gumbel32(kh0, kh1, jb + (uint32_t)(sub * 64 + c));
        float s = __fdiv_rn(__fadd_rn(l[sub], g), 0.9f);
        if (sub == 0 || s > sv) { sv = s; si = sub * 64 + c; }
      }
      argmax64(sv, si);
      // soft: scores, row max, exp (CR f32)
      float ssv[4];
#pragma unroll
      for (int sub = 0; sub < 4; ++sub) {
        float g = gumbel32(ks0, ks1, jb + (uint32_t)(sub * 64 + c));
        ssv[sub] = __fdiv_rn(__fadd_rn(l[sub], g), 0.9f);
      }
      float m = fmaxf(fmaxf(ssv[0], ssv[1]), fmaxf(ssv[2], ssv[3]));
#pragma unroll
      for (int off = 32; off >= 1; off >>= 1) m = fmaxf(m, __shfl_xor(m, off));
#pragma unroll
      for (int sub = 0; sub < 4; ++sub)
        ssbuf[r * 257 + sub * 64 + c] = exp32cr(__fsub_rn(ssv[sub], m));
      if (c == 0) { selL[r] = si; idxL[r] = bi; }
    }
  }
  __syncthreads();

  // ph2b: numpy-pairwise softmax denom, ws, wstar (one thread per row)
  if (t < RPB) {
    const int r = t, n = n0 + r;
    const float* a = xp + RPB * 256 + r * 257;
    float S = __fadd_rn(pw128(a), pw128(a + 128));
    int sel = selL[r];
    float wsv = __fdiv_rn(a[sel], S);
    wsL[r] = __fadd_rn(__fsub_rn(1.0f, wsv), wsv);
    out[(size_t)NROWS * DIM + (size_t)n * 4 + stage] = (float)idxL[r];
  }
  __syncthreads();

  // ph3: p = fl32(wstar * C[sel][col]); out_sum RMW (ref stage order); pbuf = p
#pragma unroll 4
  for (int r = 0; r < RPB; ++r) {
    float p = __fmul_rn(wsL[r], Cbi[(size_t)selL[r] * 512 + t]);
    size_t o = (size_t)(n0 + r) * 512 + t;
    out[o] = (stage == 0) ? p : __fadd_rn(out[o], p);
    if (stage < 3) xp[r * 512 + t] = p;   // pbuf overlays dead lg+ssbuf
  }

  // ph4: x_next = x - p @ W_rnn (seq-d FMA); write to global (in-place own rows)
  if (stage < 3) {
    __syncthreads();
    const int e0 = tc * 4;
    float acc[4][4];
#pragma unroll
    for (int rr = 0; rr < 4; ++rr)
#pragma unroll
      for (int c = 0; c < 4; ++c) acc[rr][c] = 0.0f;
    for (int d = 0; d < 512; d += 4) {
      float4 w0 = *(const float4*)&Wr[(size_t)(d + 0) * 512 + e0];
      float4 w1 = *(const float4*)&Wr[(size_t)(d + 1) * 512 + e0];
      float4 w2 = *(const float4*)&Wr[(size_t)(d + 2) * 512 + e0];
      float4 w3 = *(const float4*)&Wr[(size_t)(d + 3) * 512 + e0];
#pragma unroll
      for (int rr = 0; rr < 4; ++rr) {
        float4 pv = *(const float4*)&xp[(r0 + rr) * 512 + d];
        acc[rr][0] = fmaf(pv.x, w0.x, acc[rr][0]);
        acc[rr][1] = fmaf(pv.x, w0.y, acc[rr][1]);
        acc[rr][2] = fmaf(pv.x, w0.z, acc[rr][2]);
        acc[rr][3] = fmaf(pv.x, w0.w, acc[rr][3]);
        acc[rr][0] = fmaf(pv.y, w1.x, acc[rr][0]);
        acc[rr][1] = fmaf(pv.y, w1.y, acc[rr][1]);
        acc[rr][2] = fmaf(pv.y, w1.z, acc[rr][2]);
        acc[rr][3] = fmaf(pv.y, w1.w, acc[rr][3]);
        acc[rr][0] = fmaf(pv.z, w2.x, acc[rr][0]);
        acc[rr][1] = fmaf(pv.z, w2.y, acc[rr][1]);
        acc[rr][2] = fmaf(pv.z, w2.z, acc[rr][2]);
        acc[rr][3] = fmaf(pv.z, w2.w, acc[rr][3]);
        acc[rr][0] = fmaf(pv.w, w3.x, acc[rr][0]);
        acc[rr][1] = fmaf(pv.w, w3.y, acc[rr][1]);
        acc[rr][2] = fmaf(pv.w, w3.z, acc[rr][2]);
        acc[rr][3] = fmaf(pv.w, w3.w, acc[rr][3]);
      }
    }
#pragma unroll
    for (int rr = 0; rr < 4; ++rr) {
      const int rw = r0 + rr;
      float4 xv = *(const float4*)&xrow[rw * 512 + e0];
      float4 o;
      o.x = __fsub_rn(xv.x, acc[rr][0]);
      o.y = __fsub_rn(xv.y, acc[rr][1]);
      o.z = __fsub_rn(xv.z, acc[rr][2]);
      o.w = __fsub_rn(xv.w, acc[rr][3]);
      *(float4*)&Xout[(size_t)(n0 + rw) * 512 + e0] = o;
    }
  }
}

extern "C" void kernel_launch(void* const* d_in, const int* in_sizes, int n_in,
                              void* d_out, int out_size, void* d_ws, size_t ws_size,
                              hipStream_t stream) {
  const float* x  = (const float*)d_in[0];   // [65536,512]
  const float* Cb = (const float*)d_in[1];   // [4,256,512]
  const float* A  = (const float*)d_in[2];   // [4,512,512]
  const float* Wr = (const float*)d_in[3];   // [512,512]
  float* out = (float*)d_out;
  float* ws  = (float*)d_ws;

  float* cpd  = ws;                          // 4*512*256 = 524288 f (2 MB)
  float* xcur = ws + 524288;                 // 65536*512 f (134 MB)

  // keys: fold_in(key(42), i) -> split -> (k_soft = keys[0], k_hard = keys[1])
  uint32_t kh[4][2], ks[4][2];
  for (uint32_t i = 0; i < 4; ++i) {
    uint32_t f0, f1, a0, a1, b0, b1;
    tf2x32(0u, 42u, 0u, i, f0, f1);
    tf2x32(f0, f1, 0u, 0u, a0, a1);   // keys[0] -> k_soft
    tf2x32(f0, f1, 0u, 1u, b0, b1);   // keys[1] -> k_hard
    ks[i][0] = a0; ks[i][1] = a1;
    kh[i][0] = b0; kh[i][1] = b1;
  }

  k_cproj<<<dim3(256), dim3(256), 0, stream>>>(Cb, A, cpd);

  const int NB = NROWS / RPB;  // 4096
  for (int i = 0; i < 4; ++i) {
    const float* Xi = (i == 0) ? x : xcur;
    k_stage<<<dim3(NB), dim3(THR), 0, stream>>>(
        Xi, xcur, A + (size_t)i * DIM * DIM, cpd + (size_t)i * DIM * KCB,
        Cb + (size_t)i * KCB * DIM, Wr, out,
        kh[i][0], kh[i][1], ks[i][0], ks[i][1], i);
  }
}